// Round 10
// baseline (143.983 us; speedup 1.0000x reference)
//
#include <hip/hip_runtime.h>

namespace {

constexpr int NIMG = 16;
constexpr int C1N  = 16;
constexpr int C2N  = 32;
constexpr int PART = C1N * 9;     // 144 partial scalars per partial-row

typedef __attribute__((ext_vector_type(8)))  _Float16 half8;
typedef __attribute__((ext_vector_type(16))) float    f32x16;

// Orthonormal 8-pt DCT-II matrix (f32-exact literals).
__device__ const float DCTM[8][8] = {
  {0.35355339059327373f, 0.35355339059327373f, 0.35355339059327373f, 0.35355339059327373f,
   0.35355339059327373f, 0.35355339059327373f, 0.35355339059327373f, 0.35355339059327373f},
  {0.49039264020161522f, 0.41573480615127262f, 0.27778511650980111f, 0.09754516100806413f,
  -0.09754516100806413f,-0.27778511650980111f,-0.41573480615127262f,-0.49039264020161522f},
  {0.46193976625564337f, 0.19134171618254492f,-0.19134171618254492f,-0.46193976625564337f,
  -0.46193976625564337f,-0.19134171618254492f, 0.19134171618254492f, 0.46193976625564337f},
  {0.41573480615127262f,-0.09754516100806413f,-0.49039264020161522f,-0.27778511650980111f,
   0.27778511650980111f, 0.49039264020161522f, 0.09754516100806413f,-0.41573480615127262f},
  {0.35355339059327373f,-0.35355339059327373f,-0.35355339059327373f, 0.35355339059327373f,
   0.35355339059327373f,-0.35355339059327373f,-0.35355339059327373f, 0.35355339059327373f},
  {0.27778511650980111f,-0.49039264020161522f, 0.09754516100806413f, 0.41573480615127262f,
  -0.41573480615127262f,-0.09754516100806413f, 0.49039264020161522f,-0.27778511650980111f},
  {0.19134171618254492f,-0.46193976625564337f, 0.46193976625564337f,-0.19134171618254492f,
  -0.19134171618254492f, 0.46193976625564337f,-0.46193976625564337f, 0.19134171618254492f},
  {0.09754516100806413f,-0.27778511650980111f, 0.41573480615127262f,-0.49039264020161522f,
   0.49039264020161522f,-0.41573480615127262f, 0.27778511650980111f,-0.09754516100806413f},
};

// Build M (1024 x 80, fp16) in A-fragment order for v_mfma_f32_32x32x16_f16.
// Verified rounds 7-9 (absmax 9.8e-4). frag f = (rt*5 + c)*64 + lane holds
// A[row = rt*32 + (lane&31), k = c*16 + (lane>>5)*8 + b].
// k-chunk 4 is the bias column (paired with a ones-B fragment).
__global__ __launch_bounds__(256) void setup_M(
    const float* __restrict__ w1, const float* __restrict__ b1,
    _Float16* __restrict__ Mf)
{
  const int f = blockIdx.x * 256 + threadIdx.x;
  if (f >= 32 * 5 * 64) return;
  const int l  = f & 63;
  const int rc = f >> 6;
  const int c  = rc % 5;
  const int rt = rc / 5;
  const int ch = rt >> 1;
  const int hi = l >> 5;
  const int s  = (rt & 1) * 32 + (l & 31);
  const int i = s >> 3, j = s & 7;

  half8 e;
  if (c == 4) {
    #pragma unroll
    for (int b = 0; b < 8; ++b) e[b] = (_Float16)0.f;
    if (hi == 0) e[0] = (_Float16)b1[ch];
  } else {
    #pragma unroll
    for (int b = 0; b < 8; ++b) {
      const int k = c * 16 + hi * 8 + b;
      const int u = k >> 3, v = k & 7;
      float acc = 0.f;
      for (int di = 0; di < 3; ++di) {
        const int ii = i + di - 1;
        if (ii < 0 || ii > 7) continue;
        for (int dj = 0; dj < 3; ++dj) {
          const int jj = j + dj - 1;
          if (jj < 0 || jj > 7) continue;
          acc = fmaf(w1[ch * 9 + di * 3 + dj], DCTM[ii][u] * DCTM[jj][v], acc);
        }
      }
      e[b] = (_Float16)acc;
    }
  }
  *reinterpret_cast<half8*>(Mf + (size_t)f * 8) = e;
}

// 4096 single-wave blocks (R7's proven block shape, 2x the TLP):
// bid = hs*512 + g; hs in [0,8): slice = hs>>1 (channel quartet of M),
// chp = hs&1 (channel pair within quartet). g in [0,512): img = g>>5,
// 128 patches (4 col-tiles). Per wave: stage B once, 2 channels x 2
// row-tiles x 4 col-tiles x 5 MFMA = 80 MFMAs, ReLU + 9 border-class sums,
// 4-level DPP reduce, contention-free partial stores. Then fused finish:
// per-image done-counter (16 counters, 256 increments each — NOT round-8's
// 589k-atomic fan-in); the 256th block re-reads the image's 128 partial
// rows in fixed order (deterministic regardless of finisher identity) and
// writes the 32 outputs.
__global__ __launch_bounds__(64, 2) void gemm_fused(
    const float* __restrict__ x, const _Float16* __restrict__ Mf,
    float* __restrict__ partials, const float* __restrict__ w2,
    const float* __restrict__ b2, unsigned int* __restrict__ img_cnt,
    float* __restrict__ out)
{
  const int bid   = blockIdx.x;
  const int hs    = bid >> 9;
  const int g     = bid & 511;
  const int slice = hs >> 1;
  const int chp   = hs & 1;
  const int img   = g >> 5, gi = g & 31;
  const int lane  = threadIdx.x;
  const int col   = lane & 31, hi = lane >> 5;

  // Stage B: 4 col-tiles x 4 K-chunks of fp16 patch data (128 patches).
  half8 bfrag[4][4];
  #pragma unroll
  for (int ct = 0; ct < 4; ++ct) {
    const int prow = 2 * gi + (ct >> 1);
    const int pcol = (ct & 1) * 32 + col;
    const float* pb = x + (((size_t)img * 512 + (size_t)prow * 8) * 512 + (size_t)pcol * 8);
    #pragma unroll
    for (int m = 0; m < 4; ++m) {
      const int u = 2 * m + hi;
      const float4 lo = *reinterpret_cast<const float4*>(pb + (size_t)u * 512);
      const float4 h4 = *reinterpret_cast<const float4*>(pb + (size_t)u * 512 + 4);
      half8 h;
      h[0] = (_Float16)lo.x; h[1] = (_Float16)lo.y; h[2] = (_Float16)lo.z; h[3] = (_Float16)lo.w;
      h[4] = (_Float16)h4.x; h[5] = (_Float16)h4.y; h[6] = (_Float16)h4.z; h[7] = (_Float16)h4.w;
      bfrag[ct][m] = h;
    }
  }
  const float hm0 = (hi == 0) ? 1.f : 0.f;
  const float hm1 = 1.f - hm0;
  half8 bones;                          // B for the bias K-chunk
  #pragma unroll
  for (int q = 0; q < 8; ++q) bones[q] = (_Float16)0.f;
  bones[0] = (_Float16)hm0;

  #pragma unroll 1
  for (int cc = 0; cc < 2; ++cc) {      // channel within pair
    const int chl = chp * 2 + cc;       // channel within slice
    float t_ = 0.f, r0 = 0.f, r7 = 0.f, c0 = 0.f, c7 = 0.f;
    float k00 = 0.f, k07 = 0.f, k70 = 0.f, k77 = 0.f;
    #pragma unroll
    for (int rp = 0; rp < 2; ++rp) {
      const int rtg = slice * 8 + chl * 2 + rp;
      const _Float16* ap = Mf + ((size_t)(rtg * 5) * 64 + (size_t)lane) * 8;
      const half8 a0 = *reinterpret_cast<const half8*>(ap);
      const half8 a1 = *reinterpret_cast<const half8*>(ap + 512);
      const half8 a2 = *reinterpret_cast<const half8*>(ap + 1024);
      const half8 a3 = *reinterpret_cast<const half8*>(ap + 1536);
      const half8 a4 = *reinterpret_cast<const half8*>(ap + 2048);
      #pragma unroll
      for (int ct = 0; ct < 4; ++ct) {
        f32x16 d;
        #pragma unroll
        for (int r = 0; r < 16; ++r) d[r] = 0.f;
        d = __builtin_amdgcn_mfma_f32_32x32x16_f16(a0, bfrag[ct][0], d, 0, 0, 0);
        d = __builtin_amdgcn_mfma_f32_32x32x16_f16(a1, bfrag[ct][1], d, 0, 0, 0);
        d = __builtin_amdgcn_mfma_f32_32x32x16_f16(a2, bfrag[ct][2], d, 0, 0, 0);
        d = __builtin_amdgcn_mfma_f32_32x32x16_f16(a3, bfrag[ct][3], d, 0, 0, 0);
        d = __builtin_amdgcn_mfma_f32_32x32x16_f16(a4, bones,        d, 0, 0, 0);

        // D layout (verified): i = 4*rp + (reg>>2), j = (reg&3) + 4*hi.
        float v[16];
        #pragma unroll
        for (int r = 0; r < 16; ++r) v[r] = fmaxf(d[r], 0.f);
        const float q0 = (v[0]  + v[1])  + (v[2]  + v[3]);
        const float q1 = (v[4]  + v[5])  + (v[6]  + v[7]);
        const float q2 = (v[8]  + v[9])  + (v[10] + v[11]);
        const float q3 = (v[12] + v[13]) + (v[14] + v[15]);
        t_ += (q0 + q1) + (q2 + q3);
        if (rp == 0) {
          r0 += q0;
          k00 = fmaf(hm0, v[0],  k00);
          k07 = fmaf(hm1, v[3],  k07);
        } else {
          r7 += q3;
          k70 = fmaf(hm0, v[12], k70);
          k77 = fmaf(hm1, v[15], k77);
        }
        c0 = fmaf(hm0, (v[0] + v[4]) + (v[8]  + v[12]), c0);
        c7 = fmaf(hm1, (v[3] + v[7]) + (v[11] + v[15]), c7);
      }
    }
    float vv[9] = {t_, r0, r7, c0, c7, k00, k07, k70, k77};
    #pragma unroll
    for (int q = 0; q < 9; ++q) {
      float s = vv[q];
      s += __shfl_xor(s, 1); s += __shfl_xor(s, 2);
      s += __shfl_xor(s, 4); s += __shfl_xor(s, 8);
      vv[q] = s;
    }
    if ((lane & 15) == 0) {             // lanes 0/16/32/48 -> 4 groups
      const size_t prw = (size_t)g * 4 + (lane >> 4);
      float* dst = partials + prw * PART + (size_t)(slice * 4 + chl) * 9;
      #pragma unroll
      for (int q = 0; q < 9; ++q) dst[q] = vv[q];
    }
  }

  // ---- fused finish: last block of this image reduces + writes out ----
  __threadfence();
  unsigned int old = 0;
  if (lane == 0) old = atomicAdd(&img_cnt[img], 1u);
  old = __shfl(old, 0);
  if (old == 255u) {
    __threadfence();
    const float* pb = partials + (size_t)img * 128 * PART;
    __shared__ float sacc[PART];
    for (int c = lane; c < PART; c += 64) {
      float s0 = 0.f, s1 = 0.f, s2 = 0.f, s3 = 0.f;
      for (int k = 0; k < 32; ++k) {
        s0 += pb[(size_t)(k      ) * PART + c];
        s1 += pb[(size_t)(k +  32) * PART + c];
        s2 += pb[(size_t)(k +  64) * PART + c];
        s3 += pb[(size_t)(k +  96) * PART + c];
      }
      sacc[c] = (s0 + s1) + (s2 + s3);
    }
    __syncthreads();
    if (lane < C2N) {
      float r = 0.f;
      for (int c1 = 0; c1 < C1N; ++c1) {
        const float T  = sacc[c1 * 9 + 0], R0 = sacc[c1 * 9 + 1], R7 = sacc[c1 * 9 + 2];
        const float Q0 = sacc[c1 * 9 + 3], Q7 = sacc[c1 * 9 + 4];
        const float K00 = sacc[c1 * 9 + 5], K07 = sacc[c1 * 9 + 6];
        const float K70 = sacc[c1 * 9 + 7], K77 = sacc[c1 * 9 + 8];
        const float* wp = w2 + (size_t)(lane * C1N + c1) * 9;
        #pragma unroll
        for (int di = 0; di < 3; ++di) {
          #pragma unroll
          for (int dj = 0; dj < 3; ++dj) {
            float S = T;
            if (di == 0) S -= R7;
            if (di == 2) S -= R0;
            if (dj == 0) S -= Q7;
            if (dj == 2) S -= Q0;
            if (di == 0 && dj == 0) S += K77;
            if (di == 0 && dj == 2) S += K70;
            if (di == 2 && dj == 0) S += K07;
            if (di == 2 && dj == 2) S += K00;
            r = fmaf(wp[di * 3 + dj], S, r);
          }
        }
      }
      out[img * C2N + lane] = b2[lane] + r * (1.0f / 262144.0f);
    }
  }
}

} // namespace

extern "C" void kernel_launch(void* const* d_in, const int* in_sizes, int n_in,
                              void* d_out, int out_size, void* d_ws, size_t ws_size,
                              hipStream_t stream) {
  const float* x  = (const float*)d_in[0];
  const float* w1 = (const float*)d_in[1];
  const float* b1 = (const float*)d_in[2];
  const float* w2 = (const float*)d_in[3];
  const float* b2 = (const float*)d_in[4];
  float* out      = (float*)d_out;

  // d_ws: [0,160KB) Mf; [256KB, 256KB+1.18MB) partials; [2MB, 2MB+64B) counters.
  _Float16* Mf    = (_Float16*)d_ws;
  float* partials = (float*)((char*)d_ws + 262144);
  unsigned int* img_cnt = (unsigned int*)((char*)d_ws + (2u << 20));

  hipMemsetAsync(img_cnt, 0, 64, stream);
  setup_M<<<40, 256, 0, stream>>>(w1, b1, Mf);
  gemm_fused<<<4096, 64, 0, stream>>>(x, Mf, partials, w2, b2, img_cnt, out);
}

// Round 11
// 90.417 us; speedup vs baseline: 1.5924x; 1.5924x over previous
//
#include <hip/hip_runtime.h>

namespace {

constexpr int NIMG = 16;
constexpr int C1N  = 16;
constexpr int C2N  = 32;
constexpr int PART = C1N * 9;     // 144 partial scalars per partial-row

typedef __attribute__((ext_vector_type(8)))  _Float16 half8;
typedef __attribute__((ext_vector_type(16))) float    f32x16;

// Orthonormal 8-pt DCT-II matrix (f32-exact literals).
__device__ const float DCTM[8][8] = {
  {0.35355339059327373f, 0.35355339059327373f, 0.35355339059327373f, 0.35355339059327373f,
   0.35355339059327373f, 0.35355339059327373f, 0.35355339059327373f, 0.35355339059327373f},
  {0.49039264020161522f, 0.41573480615127262f, 0.27778511650980111f, 0.09754516100806413f,
  -0.09754516100806413f,-0.27778511650980111f,-0.41573480615127262f,-0.49039264020161522f},
  {0.46193976625564337f, 0.19134171618254492f,-0.19134171618254492f,-0.46193976625564337f,
  -0.46193976625564337f,-0.19134171618254492f, 0.19134171618254492f, 0.46193976625564337f},
  {0.41573480615127262f,-0.09754516100806413f,-0.49039264020161522f,-0.27778511650980111f,
   0.27778511650980111f, 0.49039264020161522f, 0.09754516100806413f,-0.41573480615127262f},
  {0.35355339059327373f,-0.35355339059327373f,-0.35355339059327373f, 0.35355339059327373f,
   0.35355339059327373f,-0.35355339059327373f,-0.35355339059327373f, 0.35355339059327373f},
  {0.27778511650980111f,-0.49039264020161522f, 0.09754516100806413f, 0.41573480615127262f,
  -0.41573480615127262f,-0.09754516100806413f, 0.49039264020161522f,-0.27778511650980111f},
  {0.19134171618254492f,-0.46193976625564337f, 0.46193976625564337f,-0.19134171618254492f,
  -0.19134171618254492f, 0.46193976625564337f,-0.46193976625564337f, 0.19134171618254492f},
  {0.09754516100806413f,-0.27778511650980111f, 0.41573480615127262f,-0.49039264020161522f,
   0.49039264020161522f,-0.41573480615127262f, 0.27778511650980111f,-0.09754516100806413f},
};

// Build M (1024 x 64, fp16) in A-fragment order for v_mfma_f32_32x32x16_f16.
// (Bias column removed vs rounds 7-10: bias now initializes the accumulator.)
// frag f = (rt*4 + c)*64 + lane holds A[row = rt*32 + (lane&31),
// k = c*16 + (lane>>5)*8 + b], b = 0..7. Fragment math verified R7-R10.
__global__ __launch_bounds__(256) void setup_M(
    const float* __restrict__ w1, _Float16* __restrict__ Mf)
{
  const int f = blockIdx.x * 256 + threadIdx.x;
  if (f >= 32 * 4 * 64) return;
  const int l  = f & 63;
  const int rc = f >> 6;
  const int c  = rc & 3;
  const int rt = rc >> 2;
  const int ch = rt >> 1;
  const int hi = l >> 5;
  const int s  = (rt & 1) * 32 + (l & 31);
  const int i = s >> 3, j = s & 7;

  half8 e;
  #pragma unroll
  for (int b = 0; b < 8; ++b) {
    const int k = c * 16 + hi * 8 + b;
    const int u = k >> 3, v = k & 7;
    float acc = 0.f;
    for (int di = 0; di < 3; ++di) {
      const int ii = i + di - 1;
      if (ii < 0 || ii > 7) continue;
      for (int dj = 0; dj < 3; ++dj) {
        const int jj = j + dj - 1;
        if (jj < 0 || jj > 7) continue;
        acc = fmaf(w1[ch * 9 + di * 3 + dj], DCTM[ii][u] * DCTM[jj][v], acc);
      }
    }
    e[b] = (_Float16)acc;
  }
  *reinterpret_cast<half8*>(Mf + (size_t)f * 8) = e;
}

// 2048 blocks x 128 threads (2 waves, no LDS, no syncthreads, no fences —
// round 8/10 lesson: any global serialization primitive costs ~100us).
// bid -> g = bid&511 (128 patches of image g>>5, 4 col-tiles) and
// pair = bid>>9; wave task hs = pair*2 + waveid in [0,8): slice = hs>>1
// (channel quartet), chp = hs&1 (pair within quartet). Per wave: stage B
// once, 2 channels x 2 row-tiles x 4 col-tiles x 4 MFMA = 64 MFMAs
// (K=64, bias via accumulator init), ReLU + 9 border-class sums, 4-level
// DPP reduce, contention-free partial stores.
__global__ __launch_bounds__(128, 4) void gemm_kernel(
    const float* __restrict__ x, const _Float16* __restrict__ Mf,
    const float* __restrict__ b1, float* __restrict__ partials)
{
  const int bid   = blockIdx.x;
  const int g     = bid & 511;
  const int hs    = ((bid >> 9) << 1) | (threadIdx.x >> 6);
  const int slice = hs >> 1;
  const int chp   = hs & 1;
  const int img   = g >> 5, gi = g & 31;
  const int lane  = threadIdx.x & 63;
  const int col   = lane & 31, hi = lane >> 5;

  // Stage B: 4 col-tiles x 4 K-chunks of fp16 patch data (128 patches).
  half8 bfrag[4][4];
  #pragma unroll
  for (int ct = 0; ct < 4; ++ct) {
    const int prow = 2 * gi + (ct >> 1);
    const int pcol = (ct & 1) * 32 + col;
    const float* pb = x + (((size_t)img * 512 + (size_t)prow * 8) * 512 + (size_t)pcol * 8);
    #pragma unroll
    for (int m = 0; m < 4; ++m) {
      const int u = 2 * m + hi;
      const float4 lo = *reinterpret_cast<const float4*>(pb + (size_t)u * 512);
      const float4 h4 = *reinterpret_cast<const float4*>(pb + (size_t)u * 512 + 4);
      half8 h;
      h[0] = (_Float16)lo.x; h[1] = (_Float16)lo.y; h[2] = (_Float16)lo.z; h[3] = (_Float16)lo.w;
      h[4] = (_Float16)h4.x; h[5] = (_Float16)h4.y; h[6] = (_Float16)h4.z; h[7] = (_Float16)h4.w;
      bfrag[ct][m] = h;
    }
  }
  const float hm0 = (hi == 0) ? 1.f : 0.f;
  const float hm1 = 1.f - hm0;

  #pragma unroll 1
  for (int cc = 0; cc < 2; ++cc) {      // channel within pair
    const int chl = chp * 2 + cc;       // channel within slice
    const float bb = b1[slice * 4 + chl];  // wave-uniform -> accumulator init
    float t_ = 0.f, r0 = 0.f, r7 = 0.f, c0 = 0.f, c7 = 0.f;
    float k00 = 0.f, k07 = 0.f, k70 = 0.f, k77 = 0.f;
    #pragma unroll
    for (int rp = 0; rp < 2; ++rp) {
      const int rtg = slice * 8 + chl * 2 + rp;
      const _Float16* ap = Mf + ((size_t)(rtg * 4) * 64 + (size_t)lane) * 8;
      const half8 a0 = *reinterpret_cast<const half8*>(ap);
      const half8 a1 = *reinterpret_cast<const half8*>(ap + 512);
      const half8 a2 = *reinterpret_cast<const half8*>(ap + 1024);
      const half8 a3 = *reinterpret_cast<const half8*>(ap + 1536);
      #pragma unroll
      for (int ct = 0; ct < 4; ++ct) {
        f32x16 d;
        #pragma unroll
        for (int r = 0; r < 16; ++r) d[r] = bb;   // bias-initialized accum
        d = __builtin_amdgcn_mfma_f32_32x32x16_f16(a0, bfrag[ct][0], d, 0, 0, 0);
        d = __builtin_amdgcn_mfma_f32_32x32x16_f16(a1, bfrag[ct][1], d, 0, 0, 0);
        d = __builtin_amdgcn_mfma_f32_32x32x16_f16(a2, bfrag[ct][2], d, 0, 0, 0);
        d = __builtin_amdgcn_mfma_f32_32x32x16_f16(a3, bfrag[ct][3], d, 0, 0, 0);

        // D layout (verified): i = 4*rp + (reg>>2), j = (reg&3) + 4*hi.
        float v[16];
        #pragma unroll
        for (int r = 0; r < 16; ++r) v[r] = fmaxf(d[r], 0.f);
        const float q0 = (v[0]  + v[1])  + (v[2]  + v[3]);
        const float q1 = (v[4]  + v[5])  + (v[6]  + v[7]);
        const float q2 = (v[8]  + v[9])  + (v[10] + v[11]);
        const float q3 = (v[12] + v[13]) + (v[14] + v[15]);
        t_ += (q0 + q1) + (q2 + q3);
        if (rp == 0) {
          r0 += q0;
          k00 = fmaf(hm0, v[0],  k00);
          k07 = fmaf(hm1, v[3],  k07);
        } else {
          r7 += q3;
          k70 = fmaf(hm0, v[12], k70);
          k77 = fmaf(hm1, v[15], k77);
        }
        c0 = fmaf(hm0, (v[0] + v[4]) + (v[8]  + v[12]), c0);
        c7 = fmaf(hm1, (v[3] + v[7]) + (v[11] + v[15]), c7);
      }
    }
    float vv[9] = {t_, r0, r7, c0, c7, k00, k07, k70, k77};
    #pragma unroll
    for (int q = 0; q < 9; ++q) {
      float s = vv[q];
      s += __shfl_xor(s, 1); s += __shfl_xor(s, 2);
      s += __shfl_xor(s, 4); s += __shfl_xor(s, 8);
      vv[q] = s;
    }
    if ((lane & 15) == 0) {             // lanes 0/16/32/48 -> 4 groups
      const size_t prw = (size_t)g * 4 + (lane >> 4);
      float* dst = partials + prw * PART + (size_t)(slice * 4 + chl) * 9;
      #pragma unroll
      for (int q = 0; q < 9; ++q) dst[q] = vv[q];
    }
  }
}

// Per image: 576 threads = 4 chunks x 144 components over the image's 128
// partial-rows -> LDS -> fixed-order combine -> w2 contraction via
// inclusion-exclusion border sums. Fully deterministic.
__global__ __launch_bounds__(576) void finish_kernel(
    const float* __restrict__ w2, const float* __restrict__ b2,
    const float* __restrict__ partials, float* __restrict__ out)
{
  const int img  = blockIdx.x;
  const int tid  = threadIdx.x;
  const int comp = tid % PART;
  const int chnk = tid / PART;         // 0..3
  constexpr int ROWS = 128;            // partial-rows per image (32 g x 4)
  constexpr int RPC  = ROWS / 4;

  __shared__ float part[4][PART];
  __shared__ float acc[C1N][9];

  {
    float s = 0.f;
    const float* pb = partials + ((size_t)img * ROWS + (size_t)chnk * RPC) * PART + comp;
    for (int k = 0; k < RPC; ++k) s += pb[(size_t)k * PART];
    part[chnk][comp] = s;
  }
  __syncthreads();
  if (tid < PART) {
    acc[tid / 9][tid % 9] = (part[0][tid] + part[1][tid]) + (part[2][tid] + part[3][tid]);
  }
  __syncthreads();
  if (tid < C2N) {
    float r = 0.f;
    for (int c1 = 0; c1 < C1N; ++c1) {
      const float T  = acc[c1][0], R0 = acc[c1][1], R7 = acc[c1][2];
      const float Q0 = acc[c1][3], Q7 = acc[c1][4];
      const float K00 = acc[c1][5], K07 = acc[c1][6], K70 = acc[c1][7], K77 = acc[c1][8];
      const float* wp = w2 + (size_t)(tid * C1N + c1) * 9;
      #pragma unroll
      for (int di = 0; di < 3; ++di) {
        #pragma unroll
        for (int dj = 0; dj < 3; ++dj) {
          float S = T;
          if (di == 0) S -= R7;
          if (di == 2) S -= R0;
          if (dj == 0) S -= Q7;
          if (dj == 2) S -= Q0;
          if (di == 0 && dj == 0) S += K77;
          if (di == 0 && dj == 2) S += K70;
          if (di == 2 && dj == 0) S += K07;
          if (di == 2 && dj == 2) S += K00;
          r = fmaf(wp[di * 3 + dj], S, r);
        }
      }
    }
    out[img * C2N + tid] = b2[tid] + r * (1.0f / 262144.0f);
  }
}

} // namespace

extern "C" void kernel_launch(void* const* d_in, const int* in_sizes, int n_in,
                              void* d_out, int out_size, void* d_ws, size_t ws_size,
                              hipStream_t stream) {
  const float* x  = (const float*)d_in[0];
  const float* w1 = (const float*)d_in[1];
  const float* b1 = (const float*)d_in[2];
  const float* w2 = (const float*)d_in[3];
  const float* b2 = (const float*)d_in[4];
  float* out      = (float*)d_out;

  // d_ws: [0,128KB) Mf fp16 fragments; [256KB, 256KB+1.18MB) partials.
  _Float16* Mf    = (_Float16*)d_ws;
  float* partials = (float*)((char*)d_ws + 262144);

  setup_M<<<32, 256, 0, stream>>>(w1, Mf);
  gemm_kernel<<<2048, 128, 0, stream>>>(x, Mf, b1, partials);
  finish_kernel<<<NIMG, 576, 0, stream>>>(w2, b2, partials, out);
}

// Round 12
// 30.611 us; speedup vs baseline: 4.7037x; 2.9538x over previous
//
#include <hip/hip_runtime.h>

namespace {

constexpr int NIMG = 16;
constexpr int C1N  = 16;
constexpr int C2N  = 32;
constexpr int PART = C1N * 9;     // 144 partial scalars per partial-row

typedef __attribute__((ext_vector_type(8)))  _Float16 half8;
typedef __attribute__((ext_vector_type(16))) float    f32x16;

// Orthonormal 8-pt DCT-II matrix (f32-exact literals).
__device__ const float DCTM[8][8] = {
  {0.35355339059327373f, 0.35355339059327373f, 0.35355339059327373f, 0.35355339059327373f,
   0.35355339059327373f, 0.35355339059327373f, 0.35355339059327373f, 0.35355339059327373f},
  {0.49039264020161522f, 0.41573480615127262f, 0.27778511650980111f, 0.09754516100806413f,
  -0.09754516100806413f,-0.27778511650980111f,-0.41573480615127262f,-0.49039264020161522f},
  {0.46193976625564337f, 0.19134171618254492f,-0.19134171618254492f,-0.46193976625564337f,
  -0.46193976625564337f,-0.19134171618254492f, 0.19134171618254492f, 0.46193976625564337f},
  {0.41573480615127262f,-0.09754516100806413f,-0.49039264020161522f,-0.27778511650980111f,
   0.27778511650980111f, 0.49039264020161522f, 0.09754516100806413f,-0.41573480615127262f},
  {0.35355339059327373f,-0.35355339059327373f,-0.35355339059327373f, 0.35355339059327373f,
   0.35355339059327373f,-0.35355339059327373f,-0.35355339059327373f, 0.35355339059327373f},
  {0.27778511650980111f,-0.49039264020161522f, 0.09754516100806413f, 0.41573480615127262f,
  -0.41573480615127262f,-0.09754516100806413f, 0.49039264020161522f,-0.27778511650980111f},
  {0.19134171618254492f,-0.46193976625564337f, 0.46193976625564337f,-0.19134171618254492f,
  -0.19134171618254492f, 0.46193976625564337f,-0.46193976625564337f, 0.19134171618254492f},
  {0.09754516100806413f,-0.27778511650980111f, 0.41573480615127262f,-0.49039264020161522f,
   0.49039264020161522f,-0.41573480615127262f, 0.27778511650980111f,-0.09754516100806413f},
};

// Build M (1024 x 64, fp16) in A-fragment order for v_mfma_f32_32x32x16_f16.
// Bias is applied via accumulator init (absmax 3.05e-5, verified R11).
// frag f = (rt*4 + c)*64 + lane holds A[row = rt*32 + (lane&31),
// k = c*16 + (lane>>5)*8 + b], b = 0..7. Fragment math verified R7-R11.
__global__ __launch_bounds__(256) void setup_M(
    const float* __restrict__ w1, _Float16* __restrict__ Mf)
{
  const int f = blockIdx.x * 256 + threadIdx.x;
  if (f >= 32 * 4 * 64) return;
  const int l  = f & 63;
  const int rc = f >> 6;
  const int c  = rc & 3;
  const int rt = rc >> 2;
  const int ch = rt >> 1;
  const int hi = l >> 5;
  const int s  = (rt & 1) * 32 + (l & 31);
  const int i = s >> 3, j = s & 7;

  half8 e;
  #pragma unroll
  for (int b = 0; b < 8; ++b) {
    const int k = c * 16 + hi * 8 + b;
    const int u = k >> 3, v = k & 7;
    float acc = 0.f;
    for (int di = 0; di < 3; ++di) {
      const int ii = i + di - 1;
      if (ii < 0 || ii > 7) continue;
      for (int dj = 0; dj < 3; ++dj) {
        const int jj = j + dj - 1;
        if (jj < 0 || jj > 7) continue;
        acc = fmaf(w1[ch * 9 + di * 3 + dj], DCTM[ii][u] * DCTM[jj][v], acc);
      }
    }
    e[b] = (_Float16)acc;
  }
  *reinterpret_cast<half8*>(Mf + (size_t)f * 8) = e;
}

// 4096 single-wave blocks — EXACTLY round-10's proven-codegen shape
// (launch_bounds(64,2) -> compiler picks 128 VGPR, no spill; round-11
// lesson: tighter caps make the allocator spill the 64-reg B-stage),
// minus the fence/atomic tail (round-10 lesson: ~100us poison).
// bid = hs*512 + g: g -> 128 patches (4 col-tiles) of image g>>5;
// hs in [0,8): slice = hs>>1 (channel quartet), chp = hs&1 (pair).
// Per wave: stage B once, 2 channels x 2 row-tiles x 4 col-tiles x
// 4 MFMA = 64 MFMAs (K=64, bias via accumulator init), ReLU + 9
// border-class sums, 4-level DPP reduce, contention-free partial stores.
__global__ __launch_bounds__(64, 2) void gemm_kernel(
    const float* __restrict__ x, const _Float16* __restrict__ Mf,
    const float* __restrict__ b1, float* __restrict__ partials)
{
  const int bid   = blockIdx.x;
  const int hs    = bid >> 9;
  const int g     = bid & 511;
  const int slice = hs >> 1;
  const int chp   = hs & 1;
  const int img   = g >> 5, gi = g & 31;
  const int lane  = threadIdx.x;
  const int col   = lane & 31, hi = lane >> 5;

  // Stage B: 4 col-tiles x 4 K-chunks of fp16 patch data (128 patches).
  half8 bfrag[4][4];
  #pragma unroll
  for (int ct = 0; ct < 4; ++ct) {
    const int prow = 2 * gi + (ct >> 1);
    const int pcol = (ct & 1) * 32 + col;
    const float* pb = x + (((size_t)img * 512 + (size_t)prow * 8) * 512 + (size_t)pcol * 8);
    #pragma unroll
    for (int m = 0; m < 4; ++m) {
      const int u = 2 * m + hi;
      const float4 lo = *reinterpret_cast<const float4*>(pb + (size_t)u * 512);
      const float4 h4 = *reinterpret_cast<const float4*>(pb + (size_t)u * 512 + 4);
      half8 h;
      h[0] = (_Float16)lo.x; h[1] = (_Float16)lo.y; h[2] = (_Float16)lo.z; h[3] = (_Float16)lo.w;
      h[4] = (_Float16)h4.x; h[5] = (_Float16)h4.y; h[6] = (_Float16)h4.z; h[7] = (_Float16)h4.w;
      bfrag[ct][m] = h;
    }
  }
  const float hm0 = (hi == 0) ? 1.f : 0.f;
  const float hm1 = 1.f - hm0;

  #pragma unroll 1
  for (int cc = 0; cc < 2; ++cc) {      // channel within pair
    const int chl = chp * 2 + cc;       // channel within slice
    const float bb = b1[slice * 4 + chl];  // wave-uniform -> accumulator init
    float t_ = 0.f, r0 = 0.f, r7 = 0.f, c0 = 0.f, c7 = 0.f;
    float k00 = 0.f, k07 = 0.f, k70 = 0.f, k77 = 0.f;
    #pragma unroll
    for (int rp = 0; rp < 2; ++rp) {
      const int rtg = slice * 8 + chl * 2 + rp;
      const _Float16* ap = Mf + ((size_t)(rtg * 4) * 64 + (size_t)lane) * 8;
      const half8 a0 = *reinterpret_cast<const half8*>(ap);
      const half8 a1 = *reinterpret_cast<const half8*>(ap + 512);
      const half8 a2 = *reinterpret_cast<const half8*>(ap + 1024);
      const half8 a3 = *reinterpret_cast<const half8*>(ap + 1536);
      #pragma unroll
      for (int ct = 0; ct < 4; ++ct) {
        f32x16 d;
        #pragma unroll
        for (int r = 0; r < 16; ++r) d[r] = bb;   // bias-initialized accum
        d = __builtin_amdgcn_mfma_f32_32x32x16_f16(a0, bfrag[ct][0], d, 0, 0, 0);
        d = __builtin_amdgcn_mfma_f32_32x32x16_f16(a1, bfrag[ct][1], d, 0, 0, 0);
        d = __builtin_amdgcn_mfma_f32_32x32x16_f16(a2, bfrag[ct][2], d, 0, 0, 0);
        d = __builtin_amdgcn_mfma_f32_32x32x16_f16(a3, bfrag[ct][3], d, 0, 0, 0);

        // D layout (verified): i = 4*rp + (reg>>2), j = (reg&3) + 4*hi.
        float v[16];
        #pragma unroll
        for (int r = 0; r < 16; ++r) v[r] = fmaxf(d[r], 0.f);
        const float q0 = (v[0]  + v[1])  + (v[2]  + v[3]);
        const float q1 = (v[4]  + v[5])  + (v[6]  + v[7]);
        const float q2 = (v[8]  + v[9])  + (v[10] + v[11]);
        const float q3 = (v[12] + v[13]) + (v[14] + v[15]);
        t_ += (q0 + q1) + (q2 + q3);
        if (rp == 0) {
          r0 += q0;
          k00 = fmaf(hm0, v[0],  k00);
          k07 = fmaf(hm1, v[3],  k07);
        } else {
          r7 += q3;
          k70 = fmaf(hm0, v[12], k70);
          k77 = fmaf(hm1, v[15], k77);
        }
        c0 = fmaf(hm0, (v[0] + v[4]) + (v[8]  + v[12]), c0);
        c7 = fmaf(hm1, (v[3] + v[7]) + (v[11] + v[15]), c7);
      }
    }
    float vv[9] = {t_, r0, r7, c0, c7, k00, k07, k70, k77};
    #pragma unroll
    for (int q = 0; q < 9; ++q) {
      float s = vv[q];
      s += __shfl_xor(s, 1); s += __shfl_xor(s, 2);
      s += __shfl_xor(s, 4); s += __shfl_xor(s, 8);
      vv[q] = s;
    }
    if ((lane & 15) == 0) {             // lanes 0/16/32/48 -> 4 groups
      const size_t prw = (size_t)g * 4 + (lane >> 4);
      float* dst = partials + prw * PART + (size_t)(slice * 4 + chl) * 9;
      #pragma unroll
      for (int q = 0; q < 9; ++q) dst[q] = vv[q];
    }
  }
}

// Per image: 576 threads = 4 chunks x 144 components over the image's 128
// partial-rows -> LDS -> fixed-order combine -> w2 contraction via
// inclusion-exclusion border sums. Fully deterministic.
__global__ __launch_bounds__(576) void finish_kernel(
    const float* __restrict__ w2, const float* __restrict__ b2,
    const float* __restrict__ partials, float* __restrict__ out)
{
  const int img  = blockIdx.x;
  const int tid  = threadIdx.x;
  const int comp = tid % PART;
  const int chnk = tid / PART;         // 0..3
  constexpr int ROWS = 128;            // partial-rows per image (32 g x 4)
  constexpr int RPC  = ROWS / 4;

  __shared__ float part[4][PART];
  __shared__ float acc[C1N][9];

  {
    float s = 0.f;
    const float* pb = partials + ((size_t)img * ROWS + (size_t)chnk * RPC) * PART + comp;
    for (int k = 0; k < RPC; ++k) s += pb[(size_t)k * PART];
    part[chnk][comp] = s;
  }
  __syncthreads();
  if (tid < PART) {
    acc[tid / 9][tid % 9] = (part[0][tid] + part[1][tid]) + (part[2][tid] + part[3][tid]);
  }
  __syncthreads();
  if (tid < C2N) {
    float r = 0.f;
    for (int c1 = 0; c1 < C1N; ++c1) {
      const float T  = acc[c1][0], R0 = acc[c1][1], R7 = acc[c1][2];
      const float Q0 = acc[c1][3], Q7 = acc[c1][4];
      const float K00 = acc[c1][5], K07 = acc[c1][6], K70 = acc[c1][7], K77 = acc[c1][8];
      const float* wp = w2 + (size_t)(tid * C1N + c1) * 9;
      #pragma unroll
      for (int di = 0; di < 3; ++di) {
        #pragma unroll
        for (int dj = 0; dj < 3; ++dj) {
          float S = T;
          if (di == 0) S -= R7;
          if (di == 2) S -= R0;
          if (dj == 0) S -= Q7;
          if (dj == 2) S -= Q0;
          if (di == 0 && dj == 0) S += K77;
          if (di == 0 && dj == 2) S += K70;
          if (di == 2 && dj == 0) S += K07;
          if (di == 2 && dj == 2) S += K00;
          r = fmaf(wp[di * 3 + dj], S, r);
        }
      }
    }
    out[img * C2N + tid] = b2[tid] + r * (1.0f / 262144.0f);
  }
}

} // namespace

extern "C" void kernel_launch(void* const* d_in, const int* in_sizes, int n_in,
                              void* d_out, int out_size, void* d_ws, size_t ws_size,
                              hipStream_t stream) {
  const float* x  = (const float*)d_in[0];
  const float* w1 = (const float*)d_in[1];
  const float* b1 = (const float*)d_in[2];
  const float* w2 = (const float*)d_in[3];
  const float* b2 = (const float*)d_in[4];
  float* out      = (float*)d_out;

  // d_ws: [0,128KB) Mf fp16 fragments; [256KB, 256KB+1.18MB) partials.
  _Float16* Mf    = (_Float16*)d_ws;
  float* partials = (float*)((char*)d_ws + 262144);

  setup_M<<<32, 256, 0, stream>>>(w1, Mf);
  gemm_kernel<<<4096, 64, 0, stream>>>(x, Mf, b1, partials);
  finish_kernel<<<NIMG, 576, 0, stream>>>(w2, b2, partials, out);
}

// Round 13
// 30.193 us; speedup vs baseline: 4.7688x; 1.0139x over previous
//
#include <hip/hip_runtime.h>

namespace {

constexpr int NIMG = 16;
constexpr int C1N  = 16;
constexpr int C2N  = 32;
constexpr int PART = C1N * 9;     // 144 partial scalars per partial-row

typedef __attribute__((ext_vector_type(8)))  _Float16 half8;
typedef __attribute__((ext_vector_type(16))) float    f32x16;

// Orthonormal 8-pt DCT-II matrix (f32-exact literals).
__device__ const float DCTM[8][8] = {
  {0.35355339059327373f, 0.35355339059327373f, 0.35355339059327373f, 0.35355339059327373f,
   0.35355339059327373f, 0.35355339059327373f, 0.35355339059327373f, 0.35355339059327373f},
  {0.49039264020161522f, 0.41573480615127262f, 0.27778511650980111f, 0.09754516100806413f,
  -0.09754516100806413f,-0.27778511650980111f,-0.41573480615127262f,-0.49039264020161522f},
  {0.46193976625564337f, 0.19134171618254492f,-0.19134171618254492f,-0.46193976625564337f,
  -0.46193976625564337f,-0.19134171618254492f, 0.19134171618254492f, 0.46193976625564337f},
  {0.41573480615127262f,-0.09754516100806413f,-0.49039264020161522f,-0.27778511650980111f,
   0.27778511650980111f, 0.49039264020161522f, 0.09754516100806413f,-0.41573480615127262f},
  {0.35355339059327373f,-0.35355339059327373f,-0.35355339059327373f, 0.35355339059327373f,
   0.35355339059327373f,-0.35355339059327373f,-0.35355339059327373f, 0.35355339059327373f},
  {0.27778511650980111f,-0.49039264020161522f, 0.09754516100806413f, 0.41573480615127262f,
  -0.41573480615127262f,-0.09754516100806413f, 0.49039264020161522f,-0.27778511650980111f},
  {0.19134171618254492f,-0.46193976625564337f, 0.46193976625564337f,-0.19134171618254492f,
  -0.19134171618254492f, 0.46193976625564337f,-0.46193976625564337f, 0.19134171618254492f},
  {0.09754516100806413f,-0.27778511650980111f, 0.41573480615127262f,-0.49039264020161522f,
   0.49039264020161522f,-0.41573480615127262f, 0.27778511650980111f,-0.09754516100806413f},
};

// Build M (1024 x 64, fp16) in A-fragment order for v_mfma_f32_32x32x16_f16.
// Bias via accumulator init (absmax 3.05e-5, verified R11/R12).
// frag f = (rt*4 + c)*64 + lane holds A[row = rt*32 + (lane&31),
// k = c*16 + (lane>>5)*8 + b], b = 0..7. Fragment math verified R7-R12.
__global__ __launch_bounds__(256) void setup_M(
    const float* __restrict__ w1, _Float16* __restrict__ Mf)
{
  const int f = blockIdx.x * 256 + threadIdx.x;
  if (f >= 32 * 4 * 64) return;
  const int l  = f & 63;
  const int rc = f >> 6;
  const int c  = rc & 3;
  const int rt = rc >> 2;
  const int ch = rt >> 1;
  const int hi = l >> 5;
  const int s  = (rt & 1) * 32 + (l & 31);
  const int i = s >> 3, j = s & 7;

  half8 e;
  #pragma unroll
  for (int b = 0; b < 8; ++b) {
    const int k = c * 16 + hi * 8 + b;
    const int u = k >> 3, v = k & 7;
    float acc = 0.f;
    for (int di = 0; di < 3; ++di) {
      const int ii = i + di - 1;
      if (ii < 0 || ii > 7) continue;
      for (int dj = 0; dj < 3; ++dj) {
        const int jj = j + dj - 1;
        if (jj < 0 || jj > 7) continue;
        acc = fmaf(w1[ch * 9 + di * 3 + dj], DCTM[ii][u] * DCTM[jj][v], acc);
      }
    }
    e[b] = (_Float16)acc;
  }
  *reinterpret_cast<half8*>(Mf + (size_t)f * 8) = e;
}

// 4096 single-wave blocks (R12's proven shape) with ALL memory hoisted:
// 32 B-loads + 16 A-loads issue up front, one vmcnt drain, then the entire
// compute loop (64 MFMAs + epilogue) is pure-register — no in-loop memory
// waits (R12 had 4x ~200cyc L2 stalls per wave from per-rp A loads).
// Fully unrolled -> every array index compile-time (no scratch).
// bid = hs*512 + g: g -> 128 patches (4 col-tiles) of image g>>5;
// hs in [0,8): slice = hs>>1 (channel quartet), chp = hs&1 (pair).
__global__ __launch_bounds__(64, 2) void gemm_kernel(
    const float* __restrict__ x, const _Float16* __restrict__ Mf,
    const float* __restrict__ b1, float* __restrict__ partials)
{
  const int bid   = blockIdx.x;
  const int hs    = bid >> 9;
  const int g     = bid & 511;
  const int slice = hs >> 1;
  const int chp   = hs & 1;
  const int img   = g >> 5, gi = g & 31;
  const int lane  = threadIdx.x;
  const int col   = lane & 31, hi = lane >> 5;

  // ---- issue ALL global loads up front ----
  // A: 16 fragments (2 channels x 2 row-tiles x 4 K-chunks), L2-resident.
  half8 afrag[2][2][4];
  #pragma unroll
  for (int cc = 0; cc < 2; ++cc) {
    #pragma unroll
    for (int rp = 0; rp < 2; ++rp) {
      const int rtg = slice * 8 + (chp * 2 + cc) * 2 + rp;
      const _Float16* ap = Mf + ((size_t)(rtg * 4) * 64 + (size_t)lane) * 8;
      #pragma unroll
      for (int c = 0; c < 4; ++c)
        afrag[cc][rp][c] = *reinterpret_cast<const half8*>(ap + (size_t)c * 512);
    }
  }
  // B: 4 col-tiles x 4 K-chunks of fp16 patch data (128 patches).
  half8 bfrag[4][4];
  #pragma unroll
  for (int ct = 0; ct < 4; ++ct) {
    const int prow = 2 * gi + (ct >> 1);
    const int pcol = (ct & 1) * 32 + col;
    const float* pb = x + (((size_t)img * 512 + (size_t)prow * 8) * 512 + (size_t)pcol * 8);
    #pragma unroll
    for (int m = 0; m < 4; ++m) {
      const int u = 2 * m + hi;
      const float4 lo = *reinterpret_cast<const float4*>(pb + (size_t)u * 512);
      const float4 h4 = *reinterpret_cast<const float4*>(pb + (size_t)u * 512 + 4);
      half8 h;
      h[0] = (_Float16)lo.x; h[1] = (_Float16)lo.y; h[2] = (_Float16)lo.z; h[3] = (_Float16)lo.w;
      h[4] = (_Float16)h4.x; h[5] = (_Float16)h4.y; h[6] = (_Float16)h4.z; h[7] = (_Float16)h4.w;
      bfrag[ct][m] = h;
    }
  }
  const float hm0 = (hi == 0) ? 1.f : 0.f;
  const float hm1 = 1.f - hm0;
  const float bb0 = b1[slice * 4 + chp * 2 + 0];
  const float bb1 = b1[slice * 4 + chp * 2 + 1];

  // ---- pure-register compute ----
  #pragma unroll
  for (int cc = 0; cc < 2; ++cc) {
    const int chl = chp * 2 + cc;
    const float bb = cc ? bb1 : bb0;
    float t_ = 0.f, r0 = 0.f, r7 = 0.f, c0 = 0.f, c7 = 0.f;
    float k00 = 0.f, k07 = 0.f, k70 = 0.f, k77 = 0.f;
    #pragma unroll
    for (int rp = 0; rp < 2; ++rp) {
      #pragma unroll
      for (int ct = 0; ct < 4; ++ct) {
        f32x16 d;
        #pragma unroll
        for (int r = 0; r < 16; ++r) d[r] = bb;   // bias-initialized accum
        d = __builtin_amdgcn_mfma_f32_32x32x16_f16(afrag[cc][rp][0], bfrag[ct][0], d, 0, 0, 0);
        d = __builtin_amdgcn_mfma_f32_32x32x16_f16(afrag[cc][rp][1], bfrag[ct][1], d, 0, 0, 0);
        d = __builtin_amdgcn_mfma_f32_32x32x16_f16(afrag[cc][rp][2], bfrag[ct][2], d, 0, 0, 0);
        d = __builtin_amdgcn_mfma_f32_32x32x16_f16(afrag[cc][rp][3], bfrag[ct][3], d, 0, 0, 0);

        // D layout (verified): i = 4*rp + (reg>>2), j = (reg&3) + 4*hi.
        float v[16];
        #pragma unroll
        for (int r = 0; r < 16; ++r) v[r] = fmaxf(d[r], 0.f);
        const float q0 = (v[0]  + v[1])  + (v[2]  + v[3]);
        const float q1 = (v[4]  + v[5])  + (v[6]  + v[7]);
        const float q2 = (v[8]  + v[9])  + (v[10] + v[11]);
        const float q3 = (v[12] + v[13]) + (v[14] + v[15]);
        t_ += (q0 + q1) + (q2 + q3);
        if (rp == 0) {
          r0 += q0;
          k00 = fmaf(hm0, v[0],  k00);
          k07 = fmaf(hm1, v[3],  k07);
        } else {
          r7 += q3;
          k70 = fmaf(hm0, v[12], k70);
          k77 = fmaf(hm1, v[15], k77);
        }
        c0 = fmaf(hm0, (v[0] + v[4]) + (v[8]  + v[12]), c0);
        c7 = fmaf(hm1, (v[3] + v[7]) + (v[11] + v[15]), c7);
      }
    }
    float vv[9] = {t_, r0, r7, c0, c7, k00, k07, k70, k77};
    #pragma unroll
    for (int q = 0; q < 9; ++q) {
      float s = vv[q];
      s += __shfl_xor(s, 1); s += __shfl_xor(s, 2);
      s += __shfl_xor(s, 4); s += __shfl_xor(s, 8);
      vv[q] = s;
    }
    if ((lane & 15) == 0) {             // lanes 0/16/32/48 -> 4 groups
      const size_t prw = (size_t)g * 4 + (lane >> 4);
      float* dst = partials + prw * PART + (size_t)(slice * 4 + chl) * 9;
      #pragma unroll
      for (int q = 0; q < 9; ++q) dst[q] = vv[q];
    }
  }
}

// Per image: 576 threads = 4 chunks x 144 components over the image's 128
// partial-rows -> LDS -> fixed-order combine -> w2 contraction via
// inclusion-exclusion border sums. Fully deterministic.
__global__ __launch_bounds__(576) void finish_kernel(
    const float* __restrict__ w2, const float* __restrict__ b2,
    const float* __restrict__ partials, float* __restrict__ out)
{
  const int img  = blockIdx.x;
  const int tid  = threadIdx.x;
  const int comp = tid % PART;
  const int chnk = tid / PART;         // 0..3
  constexpr int ROWS = 128;            // partial-rows per image (32 g x 4)
  constexpr int RPC  = ROWS / 4;

  __shared__ float part[4][PART];
  __shared__ float acc[C1N][9];

  {
    float s = 0.f;
    const float* pb = partials + ((size_t)img * ROWS + (size_t)chnk * RPC) * PART + comp;
    for (int k = 0; k < RPC; ++k) s += pb[(size_t)k * PART];
    part[chnk][comp] = s;
  }
  __syncthreads();
  if (tid < PART) {
    acc[tid / 9][tid % 9] = (part[0][tid] + part[1][tid]) + (part[2][tid] + part[3][tid]);
  }
  __syncthreads();
  if (tid < C2N) {
    float r = 0.f;
    for (int c1 = 0; c1 < C1N; ++c1) {
      const float T  = acc[c1][0], R0 = acc[c1][1], R7 = acc[c1][2];
      const float Q0 = acc[c1][3], Q7 = acc[c1][4];
      const float K00 = acc[c1][5], K07 = acc[c1][6], K70 = acc[c1][7], K77 = acc[c1][8];
      const float* wp = w2 + (size_t)(tid * C1N + c1) * 9;
      #pragma unroll
      for (int di = 0; di < 3; ++di) {
        #pragma unroll
        for (int dj = 0; dj < 3; ++dj) {
          float S = T;
          if (di == 0) S -= R7;
          if (di == 2) S -= R0;
          if (dj == 0) S -= Q7;
          if (dj == 2) S -= Q0;
          if (di == 0 && dj == 0) S += K77;
          if (di == 0 && dj == 2) S += K70;
          if (di == 2 && dj == 0) S += K07;
          if (di == 2 && dj == 2) S += K00;
          r = fmaf(wp[di * 3 + dj], S, r);
        }
      }
    }
    out[img * C2N + tid] = b2[tid] + r * (1.0f / 262144.0f);
  }
}

} // namespace

extern "C" void kernel_launch(void* const* d_in, const int* in_sizes, int n_in,
                              void* d_out, int out_size, void* d_ws, size_t ws_size,
                              hipStream_t stream) {
  const float* x  = (const float*)d_in[0];
  const float* w1 = (const float*)d_in[1];
  const float* b1 = (const float*)d_in[2];
  const float* w2 = (const float*)d_in[3];
  const float* b2 = (const float*)d_in[4];
  float* out      = (float*)d_out;

  // d_ws: [0,128KB) Mf fp16 fragments; [256KB, 256KB+1.18MB) partials.
  _Float16* Mf    = (_Float16*)d_ws;
  float* partials = (float*)((char*)d_ws + 262144);

  setup_M<<<32, 256, 0, stream>>>(w1, Mf);
  gemm_kernel<<<4096, 64, 0, stream>>>(x, Mf, b1, partials);
  finish_kernel<<<NIMG, 576, 0, stream>>>(w2, b2, partials, out);
}